// Round 2
// baseline (669.553 us; speedup 1.0000x reference)
//
#include <hip/hip_runtime.h>

#define TT 16384
#define HH 1024
#define EE 8

typedef __attribute__((ext_vector_type(8))) short short8;
typedef __attribute__((ext_vector_type(4))) float f32x4;

__device__ inline unsigned short f2bf(float f) {
    union { float f; unsigned int u; } v; v.f = f;
    unsigned int u = v.u;
    unsigned int r = (u + 0x7FFFu + ((u >> 16) & 1u)) >> 16; // RNE
    return (unsigned short)r;
}

// ---------------------------------------------------------------------------
// Transpose + convert expert_w [E][H][H] fp32 (h-major) -> Wt [E][d][h] bf16
// so the GEMM B operand is k(=h)-contiguous ("B^T" layout).
// ---------------------------------------------------------------------------
__global__ __launch_bounds__(256) void transpose_w_kernel(
    const float* __restrict__ w, unsigned short* __restrict__ wt)
{
    __shared__ unsigned short tile[64][66]; // +2 pad breaks bank conflicts
    int bid = blockIdx.x;
    int e   = bid >> 8;            // 256 tiles (16x16 of 64x64) per expert
    int rem = bid & 255;
    int hb  = ((rem >> 4) & 15) * 64;
    int db  = (rem & 15) * 64;
    int tid = threadIdx.x;
    int c4  = (tid & 15) * 4;
    int r0  = tid >> 4;            // 0..15

    const float* we = w + (size_t)e * HH * HH;
    #pragma unroll
    for (int i = 0; i < 4; ++i) {
        int r = i * 16 + r0;
        float4 v = *(const float4*)(we + (size_t)(hb + r) * HH + db + c4);
        tile[r][c4 + 0] = f2bf(v.x);
        tile[r][c4 + 1] = f2bf(v.y);
        tile[r][c4 + 2] = f2bf(v.z);
        tile[r][c4 + 3] = f2bf(v.w);
    }
    __syncthreads();
    unsigned short* wte = wt + (size_t)e * HH * HH;
    #pragma unroll
    for (int i = 0; i < 4; ++i) {
        int dr = i * 16 + r0;
        ushort4 o;
        o.x = tile[c4 + 0][dr];
        o.y = tile[c4 + 1][dr];
        o.z = tile[c4 + 2][dr];
        o.w = tile[c4 + 3][dr];
        *(ushort4*)(wte + (size_t)(db + dr) * HH + hb + c4) = o;
    }
}

// ---------------------------------------------------------------------------
// Router (fp32 exact) + fused x->bf16 conversion + out init with bias term.
// One wave per token. Lists per expert built with atomic counters.
// ---------------------------------------------------------------------------
__global__ __launch_bounds__(256) void router_init_kernel(
    const float* __restrict__ x, const float* __restrict__ gw,
    const float* __restrict__ gb, const float* __restrict__ eb,
    float* __restrict__ out, float* __restrict__ logits,
    unsigned short* __restrict__ xb, int* __restrict__ counts,
    int* __restrict__ tokl, float* __restrict__ wl)
{
    const int lane = threadIdx.x & 63;
    const int wv   = threadIdx.x >> 6;
    const int t    = blockIdx.x * 4 + wv;

    const float* xrow = x + (size_t)t * HH;
    unsigned short* xbrow = xb + (size_t)t * HH;

    float acc[8];
    #pragma unroll
    for (int e = 0; e < 8; ++e) acc[e] = 0.0f;

    #pragma unroll
    for (int i = 0; i < 4; ++i) {
        int idx = i * 256 + lane * 4;
        float4 v = *(const float4*)(xrow + idx);
        ushort4 bv;
        bv.x = f2bf(v.x); bv.y = f2bf(v.y); bv.z = f2bf(v.z); bv.w = f2bf(v.w);
        *(ushort4*)(xbrow + idx) = bv;
        float xs[4] = {v.x, v.y, v.z, v.w};
        #pragma unroll
        for (int j = 0; j < 4; ++j) {
            const float* g = gw + (size_t)(idx + j) * EE;
            float4 g0 = *(const float4*)(g);
            float4 g1 = *(const float4*)(g + 4);
            acc[0] += xs[j] * g0.x; acc[1] += xs[j] * g0.y;
            acc[2] += xs[j] * g0.z; acc[3] += xs[j] * g0.w;
            acc[4] += xs[j] * g1.x; acc[5] += xs[j] * g1.y;
            acc[6] += xs[j] * g1.z; acc[7] += xs[j] * g1.w;
        }
    }
    // butterfly reduce across the 64-lane wave (bitwise identical per lane)
    #pragma unroll
    for (int e = 0; e < 8; ++e) {
        #pragma unroll
        for (int off = 32; off >= 1; off >>= 1)
            acc[e] += __shfl_xor(acc[e], off, 64);
    }
    float lg[8];
    #pragma unroll
    for (int e = 0; e < 8; ++e) lg[e] = acc[e] + gb[e];

    // write logits without runtime-indexing lg[] (avoid scratch, rule #20)
    float myv = 0.0f;
    #pragma unroll
    for (int e = 0; e < 8; ++e) myv = (lane == e) ? lg[e] : myv;
    if (lane < 8) logits[(size_t)t * EE + lane] = myv;

    // top-2, lowest-index tie-break (matches lax.top_k; softmax is monotone)
    int i0 = 0;
    #pragma unroll
    for (int e = 1; e < 8; ++e) if (lg[e] > lg[i0]) i0 = e;
    int i1 = (i0 == 0) ? 1 : 0;
    #pragma unroll
    for (int e = 0; e < 8; ++e) if (e != i0 && lg[e] > lg[i1]) i1 = e;

    float w0 = 1.0f / (1.0f + expf(lg[i1] - lg[i0])); // = p0/(p0+p1)
    float w1 = 1.0f - w0;

    if (lane == 0) {
        int p0 = atomicAdd(&counts[i0], 1);
        tokl[i0 * TT + p0] = t; wl[i0 * TT + p0] = w0;
        int p1 = atomicAdd(&counts[i1], 1);
        tokl[i1 * TT + p1] = t; wl[i1 * TT + p1] = w1;
    }

    // out init = w0*b[i0] + w1*b[i1] (also covers the 0xAA poison)
    const float* b0 = eb + (size_t)i0 * HH;
    const float* b1 = eb + (size_t)i1 * HH;
    float* orow = out + (size_t)t * HH;
    #pragma unroll
    for (int i = 0; i < 4; ++i) {
        int idx = i * 256 + lane * 4;
        float4 a = *(const float4*)(b0 + idx);
        float4 c = *(const float4*)(b1 + idx);
        float4 r;
        r.x = w0 * a.x + w1 * c.x;
        r.y = w0 * a.y + w1 * c.y;
        r.z = w0 * a.z + w1 * c.z;
        r.w = w0 * a.w + w1 * c.w;
        *(float4*)(orow + idx) = r;
    }
}

// ---------------------------------------------------------------------------
// Grouped gathered GEMM: for each expert e, rows = gathered tokens.
// 128x128 tile, BK=64, 4 waves (each 64x64 via 4x4 16x16x32 bf16 MFMA).
// Epilogue: atomicAdd(out[token], w * acc).
// ---------------------------------------------------------------------------
#define BM 128
#define BN 128
#define BK 64

__global__ __launch_bounds__(256) void moe_gemm_kernel(
    const unsigned short* __restrict__ xb, const unsigned short* __restrict__ wt,
    const int* __restrict__ counts, const int* __restrict__ tokl,
    const float* __restrict__ wl, float* __restrict__ out)
{
    const int NB    = HH / BN;   // 8
    const int MAXMB = TT / BM;   // 128
    int bid = blockIdx.x;
    int e   = bid / (MAXMB * NB);
    int rem = bid - e * (MAXMB * NB);
    int mb  = rem / NB;
    int nb  = rem - mb * NB;
    int cnt = counts[e];
    int row0 = mb * BM;
    if (row0 >= cnt) return;

    __shared__ __align__(16) unsigned short Alds[BM * BK];
    __shared__ __align__(16) unsigned short Blds[BN * BK];
    __shared__ int   toks[BM];
    __shared__ float wgts[BM];

    int tid = threadIdx.x;
    if (tid < BM) {
        int g = row0 + tid;
        bool ok = g < cnt;
        toks[tid] = ok ? tokl[e * TT + g] : 0;
        wgts[tid] = ok ? wl[e * TT + g] : 0.0f;
    }
    __syncthreads();

    const int lane = tid & 63;
    const int wv   = tid >> 6;
    const int wr   = wv >> 1, wc = wv & 1;
    const int mrow = wr * 64, ncol = wc * 64;

    f32x4 acc[4][4];
    #pragma unroll
    for (int m = 0; m < 4; ++m)
        #pragma unroll
        for (int n = 0; n < 4; ++n) acc[m][n] = (f32x4)0.0f;

    const unsigned short* wte = wt + (size_t)e * HH * HH + (size_t)(nb * BN) * HH;
    const int off = wv * 1024 + lane * 16; // byte offset within a 4KB round

    for (int kt = 0; kt < HH / BK; ++kt) {
        int k0 = kt * BK;
        #pragma unroll
        for (int rnd = 0; rnd < 4; ++rnd) {
            int o  = rnd * 4096 + off;
            int r  = o >> 7;     // row in tile (128B per row)
            int cb = o & 127;    // byte within row
            const unsigned short* srcA = xb + (size_t)toks[r] * HH + k0 + (cb >> 1);
            __builtin_amdgcn_global_load_lds(
                (const __attribute__((address_space(1))) void*)srcA,
                (__attribute__((address_space(3))) void*)((char*)Alds + rnd * 4096 + wv * 1024),
                16, 0, 0);
            const unsigned short* srcB = wte + (size_t)r * HH + k0 + (cb >> 1);
            __builtin_amdgcn_global_load_lds(
                (const __attribute__((address_space(1))) void*)srcB,
                (__attribute__((address_space(3))) void*)((char*)Blds + rnd * 4096 + wv * 1024),
                16, 0, 0);
        }
        __syncthreads();
        #pragma unroll
        for (int kk = 0; kk < 2; ++kk) {
            int kb = kk * 64 + (lane >> 4) * 16;
            short8 av[4], bv[4];
            #pragma unroll
            for (int m = 0; m < 4; ++m)
                av[m] = *(const short8*)((const char*)Alds + (mrow + m * 16 + (lane & 15)) * 128 + kb);
            #pragma unroll
            for (int n = 0; n < 4; ++n)
                bv[n] = *(const short8*)((const char*)Blds + (ncol + n * 16 + (lane & 15)) * 128 + kb);
            #pragma unroll
            for (int m = 0; m < 4; ++m)
                #pragma unroll
                for (int n = 0; n < 4; ++n)
                    acc[m][n] = __builtin_amdgcn_mfma_f32_16x16x32_bf16(av[m], bv[n], acc[m][n], 0, 0, 0);
        }
        __syncthreads();
    }

    // epilogue: C/D mapping col=lane&15, row=(lane>>4)*4+reg
    #pragma unroll
    for (int m = 0; m < 4; ++m) {
        int lr0 = mrow + m * 16 + ((lane >> 4) << 2);
        #pragma unroll
        for (int rg = 0; rg < 4; ++rg) {
            int lr = lr0 + rg;
            int tkn = toks[lr];
            float wg = wgts[lr];
            if (wg != 0.0f) {
                float* orow = out + (size_t)tkn * HH + nb * BN + ncol + (lane & 15);
                #pragma unroll
                for (int n = 0; n < 4; ++n)
                    atomicAdd(orow + n * 16, wg * acc[m][n][rg]);
            }
        }
    }
}

// ---------------------------------------------------------------------------
extern "C" void kernel_launch(void* const* d_in, const int* in_sizes, int n_in,
                              void* d_out, int out_size, void* d_ws, size_t ws_size,
                              hipStream_t stream) {
    const float* x  = (const float*)d_in[0];
    const float* gw = (const float*)d_in[1];
    const float* gb = (const float*)d_in[2];
    const float* ew = (const float*)d_in[3];
    const float* eb = (const float*)d_in[4];
    float* out    = (float*)d_out;
    float* logits = out + (size_t)TT * HH;

    char* w = (char*)d_ws;
    unsigned short* xb = (unsigned short*)w;                                   // 32 MB
    unsigned short* wt = (unsigned short*)(w + (size_t)TT * HH * 2);           // 16 MB
    char* p  = w + (size_t)TT * HH * 2 + (size_t)EE * HH * HH * 2;
    int*   counts = (int*)p;                                                   // 32 B (+pad)
    int*   tokl   = (int*)(p + 256);                                           // 512 KB
    float* wl     = (float*)(p + 256 + (size_t)EE * TT * 4);                   // 512 KB

    hipMemsetAsync(counts, 0, 256, stream);
    hipLaunchKernelGGL(transpose_w_kernel, dim3(EE * 256), dim3(256), 0, stream, ew, wt);
    hipLaunchKernelGGL(router_init_kernel, dim3(TT / 4), dim3(256), 0, stream,
                       x, gw, gb, eb, out, logits, xb, counts, tokl, wl);
    hipLaunchKernelGGL(moe_gemm_kernel, dim3(EE * (TT / BM) * (HH / BN)), dim3(256), 0, stream,
                       xb, wt, counts, tokl, wl, out);
}

// Round 3
// 381.631 us; speedup vs baseline: 1.7545x; 1.7545x over previous
//
#include <hip/hip_runtime.h>

#define TT 16384
#define HH 1024
#define EE 8

typedef __attribute__((ext_vector_type(8))) short short8;
typedef __attribute__((ext_vector_type(4))) float f32x4;

__device__ inline unsigned short f2bf(float f) {
    union { float f; unsigned int u; } v; v.f = f;
    unsigned int u = v.u;
    unsigned int r = (u + 0x7FFFu + ((u >> 16) & 1u)) >> 16; // RNE
    return (unsigned short)r;
}

// ---------------------------------------------------------------------------
// Transpose + convert expert_w [E][H][H] fp32 (h-major) -> Wt [E][d][h] bf16
// ---------------------------------------------------------------------------
__global__ __launch_bounds__(256) void transpose_w_kernel(
    const float* __restrict__ w, unsigned short* __restrict__ wt)
{
    __shared__ unsigned short tile[64][66];
    int bid = blockIdx.x;
    int e   = bid >> 8;
    int rem = bid & 255;
    int hb  = ((rem >> 4) & 15) * 64;
    int db  = (rem & 15) * 64;
    int tid = threadIdx.x;
    int c4  = (tid & 15) * 4;
    int r0  = tid >> 4;

    const float* we = w + (size_t)e * HH * HH;
    #pragma unroll
    for (int i = 0; i < 4; ++i) {
        int r = i * 16 + r0;
        float4 v = *(const float4*)(we + (size_t)(hb + r) * HH + db + c4);
        tile[r][c4 + 0] = f2bf(v.x);
        tile[r][c4 + 1] = f2bf(v.y);
        tile[r][c4 + 2] = f2bf(v.z);
        tile[r][c4 + 3] = f2bf(v.w);
    }
    __syncthreads();
    unsigned short* wte = wt + (size_t)e * HH * HH;
    #pragma unroll
    for (int i = 0; i < 4; ++i) {
        int dr = i * 16 + r0;
        ushort4 o;
        o.x = tile[c4 + 0][dr];
        o.y = tile[c4 + 1][dr];
        o.z = tile[c4 + 2][dr];
        o.w = tile[c4 + 3][dr];
        *(ushort4*)(wte + (size_t)(db + dr) * HH + hb + c4) = o;
    }
}

// ---------------------------------------------------------------------------
// R1: router decide — NO atomics. Logits (fp32 exact), top-2, weights,
// x->bf16, out init. Writes packed per-token record for the list builder.
// ---------------------------------------------------------------------------
__global__ __launch_bounds__(256) void router_decide_kernel(
    const float* __restrict__ x, const float* __restrict__ gw,
    const float* __restrict__ gb, const float* __restrict__ eb,
    float* __restrict__ out, float* __restrict__ logits,
    unsigned short* __restrict__ xb, int* __restrict__ tops_i,
    float* __restrict__ tops_w)
{
    const int lane = threadIdx.x & 63;
    const int wv   = threadIdx.x >> 6;
    const int t    = blockIdx.x * 4 + wv;

    const float* xrow = x + (size_t)t * HH;
    unsigned short* xbrow = xb + (size_t)t * HH;

    float acc[8];
    #pragma unroll
    for (int e = 0; e < 8; ++e) acc[e] = 0.0f;

    #pragma unroll
    for (int i = 0; i < 4; ++i) {
        int idx = i * 256 + lane * 4;
        float4 v = *(const float4*)(xrow + idx);
        ushort4 bv;
        bv.x = f2bf(v.x); bv.y = f2bf(v.y); bv.z = f2bf(v.z); bv.w = f2bf(v.w);
        *(ushort4*)(xbrow + idx) = bv;
        float xs[4] = {v.x, v.y, v.z, v.w};
        #pragma unroll
        for (int j = 0; j < 4; ++j) {
            const float* g = gw + (size_t)(idx + j) * EE;
            float4 g0 = *(const float4*)(g);
            float4 g1 = *(const float4*)(g + 4);
            acc[0] += xs[j] * g0.x; acc[1] += xs[j] * g0.y;
            acc[2] += xs[j] * g0.z; acc[3] += xs[j] * g0.w;
            acc[4] += xs[j] * g1.x; acc[5] += xs[j] * g1.y;
            acc[6] += xs[j] * g1.z; acc[7] += xs[j] * g1.w;
        }
    }
    #pragma unroll
    for (int e = 0; e < 8; ++e) {
        #pragma unroll
        for (int off = 32; off >= 1; off >>= 1)
            acc[e] += __shfl_xor(acc[e], off, 64);
    }
    float lg[8];
    #pragma unroll
    for (int e = 0; e < 8; ++e) lg[e] = acc[e] + gb[e];

    float myv = 0.0f;
    #pragma unroll
    for (int e = 0; e < 8; ++e) myv = (lane == e) ? lg[e] : myv;
    if (lane < 8) logits[(size_t)t * EE + lane] = myv;

    // top-2, lowest-index tie-break (matches lax.top_k; softmax is monotone)
    int i0 = 0;
    #pragma unroll
    for (int e = 1; e < 8; ++e) if (lg[e] > lg[i0]) i0 = e;
    int i1 = (i0 == 0) ? 1 : 0;
    #pragma unroll
    for (int e = 0; e < 8; ++e) if (e != i0 && lg[e] > lg[i1]) i1 = e;

    float w0 = 1.0f / (1.0f + expf(lg[i1] - lg[i0])); // = p0/(p0+p1)
    float w1 = 1.0f - w0;

    if (lane == 0) {
        tops_i[t] = i0 | (i1 << 3);
        tops_w[t] = w0;
    }

    // out init = w0*b[i0] + w1*b[i1] (covers the 0xAA poison)
    const float* b0 = eb + (size_t)i0 * HH;
    const float* b1 = eb + (size_t)i1 * HH;
    float* orow = out + (size_t)t * HH;
    #pragma unroll
    for (int i = 0; i < 4; ++i) {
        int idx = i * 256 + lane * 4;
        float4 a = *(const float4*)(b0 + idx);
        float4 c = *(const float4*)(b1 + idx);
        float4 r;
        r.x = w0 * a.x + w1 * c.x;
        r.y = w0 * a.y + w1 * c.y;
        r.z = w0 * a.z + w1 * c.z;
        r.w = w0 * a.w + w1 * c.w;
        *(float4*)(orow + idx) = r;
    }
}

// ---------------------------------------------------------------------------
// R2: build gather lists hierarchically. LDS histogram per block (256 tokens),
// one global atomic per expert per block (64 blocks x 8 = 512 total),
// then scattered entry writes. List order is irrelevant to the math.
// ---------------------------------------------------------------------------
__global__ __launch_bounds__(256) void build_lists_kernel(
    const int* __restrict__ tops_i, const float* __restrict__ tops_w,
    int* __restrict__ counts, int* __restrict__ tokl, float* __restrict__ wl)
{
    __shared__ int lcnt[EE];
    __shared__ int gbase[EE];
    int tid = threadIdx.x;
    if (tid < EE) lcnt[tid] = 0;
    __syncthreads();

    int t   = blockIdx.x * 256 + tid;
    int rec = tops_i[t];
    int i0  = rec & 7;
    int i1  = (rec >> 3) & 7;
    float w0 = tops_w[t];
    float w1 = 1.0f - w0;

    int r0 = atomicAdd(&lcnt[i0], 1);
    int r1 = atomicAdd(&lcnt[i1], 1);
    __syncthreads();

    if (tid < EE) gbase[tid] = atomicAdd(&counts[tid], lcnt[tid]);
    __syncthreads();

    int p0 = gbase[i0] + r0;
    tokl[i0 * TT + p0] = t; wl[i0 * TT + p0] = w0;
    int p1 = gbase[i1] + r1;
    tokl[i1 * TT + p1] = t; wl[i1 * TT + p1] = w1;
}

// ---------------------------------------------------------------------------
// Grouped gathered GEMM (unchanged from round 2): 128x128 tile, BK=64,
// 4 waves, 16x16x32 bf16 MFMA, atomicAdd epilogue onto out.
// ---------------------------------------------------------------------------
#define BM 128
#define BN 128
#define BK 64

__global__ __launch_bounds__(256) void moe_gemm_kernel(
    const unsigned short* __restrict__ xb, const unsigned short* __restrict__ wt,
    const int* __restrict__ counts, const int* __restrict__ tokl,
    const float* __restrict__ wl, float* __restrict__ out)
{
    const int NB    = HH / BN;   // 8
    const int MAXMB = TT / BM;   // 128
    int bid = blockIdx.x;
    int e   = bid / (MAXMB * NB);
    int rem = bid - e * (MAXMB * NB);
    int mb  = rem / NB;
    int nb  = rem - mb * NB;
    int cnt = counts[e];
    int row0 = mb * BM;
    if (row0 >= cnt) return;

    __shared__ __align__(16) unsigned short Alds[BM * BK];
    __shared__ __align__(16) unsigned short Blds[BN * BK];
    __shared__ int   toks[BM];
    __shared__ float wgts[BM];

    int tid = threadIdx.x;
    if (tid < BM) {
        int g = row0 + tid;
        bool ok = g < cnt;
        toks[tid] = ok ? tokl[e * TT + g] : 0;
        wgts[tid] = ok ? wl[e * TT + g] : 0.0f;
    }
    __syncthreads();

    const int lane = tid & 63;
    const int wv   = tid >> 6;
    const int wr   = wv >> 1, wc = wv & 1;
    const int mrow = wr * 64, ncol = wc * 64;

    f32x4 acc[4][4];
    #pragma unroll
    for (int m = 0; m < 4; ++m)
        #pragma unroll
        for (int n = 0; n < 4; ++n) acc[m][n] = (f32x4)0.0f;

    const unsigned short* wte = wt + (size_t)e * HH * HH + (size_t)(nb * BN) * HH;
    const int off = wv * 1024 + lane * 16;

    for (int kt = 0; kt < HH / BK; ++kt) {
        int k0 = kt * BK;
        #pragma unroll
        for (int rnd = 0; rnd < 4; ++rnd) {
            int o  = rnd * 4096 + off;
            int r  = o >> 7;
            int cb = o & 127;
            const unsigned short* srcA = xb + (size_t)toks[r] * HH + k0 + (cb >> 1);
            __builtin_amdgcn_global_load_lds(
                (const __attribute__((address_space(1))) void*)srcA,
                (__attribute__((address_space(3))) void*)((char*)Alds + rnd * 4096 + wv * 1024),
                16, 0, 0);
            const unsigned short* srcB = wte + (size_t)r * HH + k0 + (cb >> 1);
            __builtin_amdgcn_global_load_lds(
                (const __attribute__((address_space(1))) void*)srcB,
                (__attribute__((address_space(3))) void*)((char*)Blds + rnd * 4096 + wv * 1024),
                16, 0, 0);
        }
        __syncthreads();
        #pragma unroll
        for (int kk = 0; kk < 2; ++kk) {
            int kb = kk * 64 + (lane >> 4) * 16;
            short8 av[4], bv[4];
            #pragma unroll
            for (int m = 0; m < 4; ++m)
                av[m] = *(const short8*)((const char*)Alds + (mrow + m * 16 + (lane & 15)) * 128 + kb);
            #pragma unroll
            for (int n = 0; n < 4; ++n)
                bv[n] = *(const short8*)((const char*)Blds + (ncol + n * 16 + (lane & 15)) * 128 + kb);
            #pragma unroll
            for (int m = 0; m < 4; ++m)
                #pragma unroll
                for (int n = 0; n < 4; ++n)
                    acc[m][n] = __builtin_amdgcn_mfma_f32_16x16x32_bf16(av[m], bv[n], acc[m][n], 0, 0, 0);
        }
        __syncthreads();
    }

    #pragma unroll
    for (int m = 0; m < 4; ++m) {
        int lr0 = mrow + m * 16 + ((lane >> 4) << 2);
        #pragma unroll
        for (int rg = 0; rg < 4; ++rg) {
            int lr = lr0 + rg;
            int tkn = toks[lr];
            float wg = wgts[lr];
            if (wg != 0.0f) {
                float* orow = out + (size_t)tkn * HH + nb * BN + ncol + (lane & 15);
                #pragma unroll
                for (int n = 0; n < 4; ++n)
                    atomicAdd(orow + n * 16, wg * acc[m][n][rg]);
            }
        }
    }
}

// ---------------------------------------------------------------------------
extern "C" void kernel_launch(void* const* d_in, const int* in_sizes, int n_in,
                              void* d_out, int out_size, void* d_ws, size_t ws_size,
                              hipStream_t stream) {
    const float* x  = (const float*)d_in[0];
    const float* gw = (const float*)d_in[1];
    const float* gb = (const float*)d_in[2];
    const float* ew = (const float*)d_in[3];
    const float* eb = (const float*)d_in[4];
    float* out    = (float*)d_out;
    float* logits = out + (size_t)TT * HH;

    char* w = (char*)d_ws;
    unsigned short* xb = (unsigned short*)w;                                   // 32 MB
    unsigned short* wt = (unsigned short*)(w + (size_t)TT * HH * 2);           // 16 MB
    char* p  = w + (size_t)TT * HH * 2 + (size_t)EE * HH * HH * 2;
    int*   counts = (int*)p;                                                   // 32 B (+pad)
    int*   tokl   = (int*)(p + 256);                                           // 512 KB
    float* wl     = (float*)(p + 256 + (size_t)EE * TT * 4);                   // 512 KB
    int*   tops_i = (int*)(p + 256 + 2 * (size_t)EE * TT * 4);                 // 64 KB
    float* tops_w = (float*)(p + 256 + 2 * (size_t)EE * TT * 4 + TT * 4);      // 64 KB

    hipMemsetAsync(counts, 0, 256, stream);
    hipLaunchKernelGGL(transpose_w_kernel, dim3(EE * 256), dim3(256), 0, stream, ew, wt);
    hipLaunchKernelGGL(router_decide_kernel, dim3(TT / 4), dim3(256), 0, stream,
                       x, gw, gb, eb, out, logits, xb, tops_i, tops_w);
    hipLaunchKernelGGL(build_lists_kernel, dim3(TT / 256), dim3(256), 0, stream,
                       tops_i, tops_w, counts, tokl, wl);
    hipLaunchKernelGGL(moe_gemm_kernel, dim3(EE * (TT / BM) * (HH / BN)), dim3(256), 0, stream,
                       xb, wt, counts, tokl, wl, out);
}

// Round 4
// 323.099 us; speedup vs baseline: 2.0723x; 1.1812x over previous
//
#include <hip/hip_runtime.h>

#define TT 16384
#define HH 1024
#define EE 8

typedef __attribute__((ext_vector_type(8))) short short8;
typedef __attribute__((ext_vector_type(4))) float f32x4;

__device__ inline unsigned short f2bf(float f) {
    union { float f; unsigned int u; } v; v.f = f;
    unsigned int u = v.u;
    unsigned int r = (u + 0x7FFFu + ((u >> 16) & 1u)) >> 16; // RNE
    return (unsigned short)r;
}

// ---------------------------------------------------------------------------
// Transpose + convert expert_w [E][H][H] fp32 (h-major) -> Wt [E][d][h] bf16
// ---------------------------------------------------------------------------
__global__ __launch_bounds__(256) void transpose_w_kernel(
    const float* __restrict__ w, unsigned short* __restrict__ wt)
{
    __shared__ unsigned short tile[64][66];
    int bid = blockIdx.x;
    int e   = bid >> 8;
    int rem = bid & 255;
    int hb  = ((rem >> 4) & 15) * 64;
    int db  = (rem & 15) * 64;
    int tid = threadIdx.x;
    int c4  = (tid & 15) * 4;
    int r0  = tid >> 4;

    const float* we = w + (size_t)e * HH * HH;
    #pragma unroll
    for (int i = 0; i < 4; ++i) {
        int r = i * 16 + r0;
        float4 v = *(const float4*)(we + (size_t)(hb + r) * HH + db + c4);
        tile[r][c4 + 0] = f2bf(v.x);
        tile[r][c4 + 1] = f2bf(v.y);
        tile[r][c4 + 2] = f2bf(v.z);
        tile[r][c4 + 3] = f2bf(v.w);
    }
    __syncthreads();
    unsigned short* wte = wt + (size_t)e * HH * HH;
    #pragma unroll
    for (int i = 0; i < 4; ++i) {
        int dr = i * 16 + r0;
        ushort4 o;
        o.x = tile[c4 + 0][dr];
        o.y = tile[c4 + 1][dr];
        o.z = tile[c4 + 2][dr];
        o.w = tile[c4 + 3][dr];
        *(ushort4*)(wte + (size_t)(db + dr) * HH + hb + c4) = o;
    }
}

// ---------------------------------------------------------------------------
// R1: router decide — gw transposed into LDS (scattered-gather fix).
// 16 tokens per block (4 per wave). No atomics. Writes logits, packed top-2,
// x->bf16, and out init (weighted bias, covers 0xAA poison).
// ---------------------------------------------------------------------------
__global__ __launch_bounds__(256) void router_decide_kernel(
    const float* __restrict__ x, const float* __restrict__ gw,
    const float* __restrict__ gb, const float* __restrict__ eb,
    float* __restrict__ out, float* __restrict__ logits,
    unsigned short* __restrict__ xb, int* __restrict__ tops_i,
    float* __restrict__ tops_w)
{
    __shared__ float gwt[EE][HH];   // 32 KB: gwt[e][h] = gw[h][e]
    int tid = threadIdx.x;
    for (int i = tid; i < (HH * EE) / 4; i += 256) {
        float4 v = ((const float4*)gw)[i];
        int b4 = i * 4;
        gwt[(b4 + 0) & 7][(b4 + 0) >> 3] = v.x;
        gwt[(b4 + 1) & 7][(b4 + 1) >> 3] = v.y;
        gwt[(b4 + 2) & 7][(b4 + 2) >> 3] = v.z;
        gwt[(b4 + 3) & 7][(b4 + 3) >> 3] = v.w;
    }
    __syncthreads();

    const int lane = tid & 63;
    const int wv   = tid >> 6;

    for (int tk = 0; tk < 4; ++tk) {
        const int t = blockIdx.x * 16 + wv * 4 + tk;
        const float* xrow = x + (size_t)t * HH;
        unsigned short* xbrow = xb + (size_t)t * HH;

        float acc[8];
        #pragma unroll
        for (int e = 0; e < 8; ++e) acc[e] = 0.0f;

        #pragma unroll
        for (int i = 0; i < 4; ++i) {
            int idx = i * 256 + lane * 4;
            float4 v = *(const float4*)(xrow + idx);
            ushort4 bv;
            bv.x = f2bf(v.x); bv.y = f2bf(v.y); bv.z = f2bf(v.z); bv.w = f2bf(v.w);
            *(ushort4*)(xbrow + idx) = bv;
            #pragma unroll
            for (int e = 0; e < 8; ++e) {
                float4 g = *(const float4*)(&gwt[e][idx]);
                acc[e] += v.x * g.x + v.y * g.y + v.z * g.z + v.w * g.w;
            }
        }
        // butterfly reduce across the 64-lane wave (bitwise identical per lane)
        #pragma unroll
        for (int e = 0; e < 8; ++e) {
            #pragma unroll
            for (int off = 32; off >= 1; off >>= 1)
                acc[e] += __shfl_xor(acc[e], off, 64);
        }
        float lg[8];
        #pragma unroll
        for (int e = 0; e < 8; ++e) lg[e] = acc[e] + gb[e];

        float myv = 0.0f;
        #pragma unroll
        for (int e = 0; e < 8; ++e) myv = (lane == e) ? lg[e] : myv;
        if (lane < 8) logits[(size_t)t * EE + lane] = myv;

        // top-2, lowest-index tie-break (matches lax.top_k; softmax monotone)
        int i0 = 0;
        #pragma unroll
        for (int e = 1; e < 8; ++e) if (lg[e] > lg[i0]) i0 = e;
        int i1 = (i0 == 0) ? 1 : 0;
        #pragma unroll
        for (int e = 0; e < 8; ++e) if (e != i0 && lg[e] > lg[i1]) i1 = e;

        float w0 = 1.0f / (1.0f + expf(lg[i1] - lg[i0])); // = p0/(p0+p1)
        float w1 = 1.0f - w0;

        if (lane == 0) {
            tops_i[t] = i0 | (i1 << 3);
            tops_w[t] = w0;
        }

        // out init = w0*b[i0] + w1*b[i1]
        const float* b0 = eb + (size_t)i0 * HH;
        const float* b1 = eb + (size_t)i1 * HH;
        float* orow = out + (size_t)t * HH;
        #pragma unroll
        for (int i = 0; i < 4; ++i) {
            int idx = i * 256 + lane * 4;
            float4 a = *(const float4*)(b0 + idx);
            float4 c = *(const float4*)(b1 + idx);
            float4 r;
            r.x = w0 * a.x + w1 * c.x;
            r.y = w0 * a.y + w1 * c.y;
            r.z = w0 * a.z + w1 * c.z;
            r.w = w0 * a.w + w1 * c.w;
            *(float4*)(orow + idx) = r;
        }
    }
}

// ---------------------------------------------------------------------------
// R2: build gather lists hierarchically (LDS histogram, 8 global atomics
// per block of 256 tokens).
// ---------------------------------------------------------------------------
__global__ __launch_bounds__(256) void build_lists_kernel(
    const int* __restrict__ tops_i, const float* __restrict__ tops_w,
    int* __restrict__ counts, int* __restrict__ tokl, float* __restrict__ wl)
{
    __shared__ int lcnt[EE];
    __shared__ int gbase[EE];
    int tid = threadIdx.x;
    if (tid < EE) lcnt[tid] = 0;
    __syncthreads();

    int t   = blockIdx.x * 256 + tid;
    int rec = tops_i[t];
    int i0  = rec & 7;
    int i1  = (rec >> 3) & 7;
    float w0 = tops_w[t];
    float w1 = 1.0f - w0;

    int r0 = atomicAdd(&lcnt[i0], 1);
    int r1 = atomicAdd(&lcnt[i1], 1);
    __syncthreads();

    if (tid < EE) gbase[tid] = atomicAdd(&counts[tid], lcnt[tid]);
    __syncthreads();

    int p0 = gbase[i0] + r0;
    tokl[i0 * TT + p0] = t; wl[i0 * TT + p0] = w0;
    int p1 = gbase[i1] + r1;
    tokl[i1 * TT + p1] = t; wl[i1 * TT + p1] = w1;
}

// ---------------------------------------------------------------------------
// Grouped gathered GEMM: 128x128 tile, BK=64, 4 waves, 16x16x32 bf16 MFMA,
// atomicAdd epilogue. T1 XCD swizzle: bid&7 -> XCD -> expert; each XCD owns
// one expert (2MB Wt panel + concurrent A-tiles fit its 4MB L2).
// ---------------------------------------------------------------------------
#define BM 128
#define BN 128
#define BK 64

__global__ __launch_bounds__(256) void moe_gemm_kernel(
    const unsigned short* __restrict__ xb, const unsigned short* __restrict__ wt,
    const int* __restrict__ counts, const int* __restrict__ tokl,
    const float* __restrict__ wl, float* __restrict__ out)
{
    // grid = 8 XCDs * 128 mb * 8 nb = 8192; HW assigns bid -> XCD bid%8.
    int bid = blockIdx.x;
    int e   = bid & 7;            // expert == XCD
    int j   = bid >> 3;           // 0..1023, nb-minor => consecutive share mb
    int mb  = j >> 3;
    int nb  = j & 7;
    int cnt = counts[e];
    int row0 = mb * BM;
    if (row0 >= cnt) return;

    __shared__ __align__(16) unsigned short Alds[BM * BK];
    __shared__ __align__(16) unsigned short Blds[BN * BK];
    __shared__ int   toks[BM];
    __shared__ float wgts[BM];

    int tid = threadIdx.x;
    if (tid < BM) {
        int g = row0 + tid;
        bool ok = g < cnt;
        toks[tid] = ok ? tokl[e * TT + g] : 0;
        wgts[tid] = ok ? wl[e * TT + g] : 0.0f;
    }
    __syncthreads();

    const int lane = tid & 63;
    const int wv   = tid >> 6;
    const int wr   = wv >> 1, wc = wv & 1;
    const int mrow = wr * 64, ncol = wc * 64;

    f32x4 acc[4][4];
    #pragma unroll
    for (int m = 0; m < 4; ++m)
        #pragma unroll
        for (int n = 0; n < 4; ++n) acc[m][n] = (f32x4)0.0f;

    const unsigned short* wte = wt + (size_t)e * HH * HH + (size_t)(nb * BN) * HH;
    const int off = wv * 1024 + lane * 16;

    for (int kt = 0; kt < HH / BK; ++kt) {
        int k0 = kt * BK;
        #pragma unroll
        for (int rnd = 0; rnd < 4; ++rnd) {
            int o  = rnd * 4096 + off;
            int r  = o >> 7;
            int cb = o & 127;
            const unsigned short* srcA = xb + (size_t)toks[r] * HH + k0 + (cb >> 1);
            __builtin_amdgcn_global_load_lds(
                (const __attribute__((address_space(1))) void*)srcA,
                (__attribute__((address_space(3))) void*)((char*)Alds + rnd * 4096 + wv * 1024),
                16, 0, 0);
            const unsigned short* srcB = wte + (size_t)r * HH + k0 + (cb >> 1);
            __builtin_amdgcn_global_load_lds(
                (const __attribute__((address_space(1))) void*)srcB,
                (__attribute__((address_space(3))) void*)((char*)Blds + rnd * 4096 + wv * 1024),
                16, 0, 0);
        }
        __syncthreads();
        #pragma unroll
        for (int kk = 0; kk < 2; ++kk) {
            int kb = kk * 64 + (lane >> 4) * 16;
            short8 av[4], bv[4];
            #pragma unroll
            for (int m = 0; m < 4; ++m)
                av[m] = *(const short8*)((const char*)Alds + (mrow + m * 16 + (lane & 15)) * 128 + kb);
            #pragma unroll
            for (int n = 0; n < 4; ++n)
                bv[n] = *(const short8*)((const char*)Blds + (ncol + n * 16 + (lane & 15)) * 128 + kb);
            #pragma unroll
            for (int m = 0; m < 4; ++m)
                #pragma unroll
                for (int n = 0; n < 4; ++n)
                    acc[m][n] = __builtin_amdgcn_mfma_f32_16x16x32_bf16(av[m], bv[n], acc[m][n], 0, 0, 0);
        }
        __syncthreads();
    }

    #pragma unroll
    for (int m = 0; m < 4; ++m) {
        int lr0 = mrow + m * 16 + ((lane >> 4) << 2);
        #pragma unroll
        for (int rg = 0; rg < 4; ++rg) {
            int lr = lr0 + rg;
            int tkn = toks[lr];
            float wg = wgts[lr];
            if (wg != 0.0f) {
                float* orow = out + (size_t)tkn * HH + nb * BN + ncol + (lane & 15);
                #pragma unroll
                for (int n = 0; n < 4; ++n)
                    atomicAdd(orow + n * 16, wg * acc[m][n][rg]);
            }
        }
    }
}

// ---------------------------------------------------------------------------
extern "C" void kernel_launch(void* const* d_in, const int* in_sizes, int n_in,
                              void* d_out, int out_size, void* d_ws, size_t ws_size,
                              hipStream_t stream) {
    const float* x  = (const float*)d_in[0];
    const float* gw = (const float*)d_in[1];
    const float* gb = (const float*)d_in[2];
    const float* ew = (const float*)d_in[3];
    const float* eb = (const float*)d_in[4];
    float* out    = (float*)d_out;
    float* logits = out + (size_t)TT * HH;

    char* w = (char*)d_ws;
    unsigned short* xb = (unsigned short*)w;                                   // 32 MB
    unsigned short* wt = (unsigned short*)(w + (size_t)TT * HH * 2);           // 16 MB
    char* p  = w + (size_t)TT * HH * 2 + (size_t)EE * HH * HH * 2;
    int*   counts = (int*)p;                                                   // 32 B (+pad)
    int*   tokl   = (int*)(p + 256);                                           // 512 KB
    float* wl     = (float*)(p + 256 + (size_t)EE * TT * 4);                   // 512 KB
    int*   tops_i = (int*)(p + 256 + 2 * (size_t)EE * TT * 4);                 // 64 KB
    float* tops_w = (float*)(p + 256 + 2 * (size_t)EE * TT * 4 + TT * 4);      // 64 KB

    hipMemsetAsync(counts, 0, 256, stream);
    hipLaunchKernelGGL(transpose_w_kernel, dim3(EE * 256), dim3(256), 0, stream, ew, wt);
    hipLaunchKernelGGL(router_decide_kernel, dim3(TT / 16), dim3(256), 0, stream,
                       x, gw, gb, eb, out, logits, xb, tops_i, tops_w);
    hipLaunchKernelGGL(build_lists_kernel, dim3(TT / 256), dim3(256), 0, stream,
                       tops_i, tops_w, counts, tokl, wl);
    hipLaunchKernelGGL(moe_gemm_kernel, dim3(EE * (TT / BM) * (HH / BN)), dim3(256), 0, stream,
                       xb, wt, counts, tokl, wl, out);
}